// Round 14
// baseline (171.050 us; speedup 1.0000x reference)
//
#include <hip/hip_runtime.h>
#include <hip/hip_bf16.h>

typedef __bf16 bf16;
typedef __bf16 bf16x4 __attribute__((ext_vector_type(4)));
typedef __bf16 bf16x8 __attribute__((ext_vector_type(8)));
typedef float f32x4 __attribute__((ext_vector_type(4)));
typedef float f32x16 __attribute__((ext_vector_type(16)));

#define NB 8
#define NS 2048
#define ND 512

static __device__ __forceinline__ f32x4 mfma16(bf16x8 a, bf16x8 b, f32x4 c) {
  return __builtin_amdgcn_mfma_f32_16x16x32_bf16(a, b, c, 0, 0, 0);
}
static __device__ __forceinline__ f32x16 mfma32(bf16x8 a, bf16x8 b, f32x16 c) {
  return __builtin_amdgcn_mfma_f32_32x32x16_bf16(a, b, c, 0, 0, 0);
}
static __device__ __forceinline__ void async16(const bf16* g, bf16* l) {
  __builtin_amdgcn_global_load_lds((const __attribute__((address_space(1))) void*)g,
                                   (__attribute__((address_space(3))) void*)l, 16, 0, 0);
}

#define WAVE_VM0() asm volatile("s_waitcnt vmcnt(0)" ::: "memory")
#define BLK_BAR() do { asm volatile("s_waitcnt lgkmcnt(0)" ::: "memory"); \
  __builtin_amdgcn_s_barrier(); __builtin_amdgcn_sched_barrier(0); } while (0)

// ---- kernel 0: W[k][n] (f32) -> Wt[z][n][k^((n&7)<<3)] (bf16, pre-swizzled).
// Wq additionally scaled by rsqrt(512)*log2e (folds softmax scale into Q).
__global__ void wconv_kernel(const float* __restrict__ Wq,
                             const float* __restrict__ Wk,
                             const float* __restrict__ Wv,
                             bf16* __restrict__ Wt) {
  __shared__ float buf[64][65];
  const int z = blockIdx.z;
  const float* W = (z == 0) ? Wq : (z == 1) ? Wk : Wv;
  const float scale = (z == 0) ? 0.063763537f : 1.0f;
  const int k0 = blockIdx.x * 64, n0 = blockIdx.y * 64;
  const int t = threadIdx.x;
#pragma unroll
  for (int i = 0; i < 16; ++i) {
    int idx = i * 256 + t;
    int kk = idx >> 6, nn = idx & 63;
    buf[kk][nn] = W[(size_t)(k0 + kk) * 512 + n0 + nn];
  }
  __syncthreads();
#pragma unroll
  for (int i = 0; i < 16; ++i) {
    int idx = i * 256 + t;
    int nn = idx >> 6, kk = idx & 63;
    Wt[(size_t)z * 262144 + (size_t)(n0 + nn) * 512 + k0 + (kk ^ ((nn & 7) << 3))] =
        (bf16)(buf[kk][nn] * scale);
  }
}

// ---- kernel 1: fused 3x projection (unchanged from round 11) ----
__launch_bounds__(256)
__global__ void proj_kernel(const float* __restrict__ Xq,
                            const float* __restrict__ Xk,
                            const float* __restrict__ Xv,
                            const bf16* __restrict__ Wt,
                            bf16* __restrict__ Cq,
                            bf16* __restrict__ Ck,
                            bf16* __restrict__ Cv) {
  __shared__ bf16 As[2][128][72];
  __shared__ bf16 WsL[2][8192];
  const int z = blockIdx.z;
  const float* A = (z == 0) ? Xq : (z == 1) ? Xk : Xv;
  const bf16* Wz = Wt + (size_t)z * 262144;
  bf16* C = (z == 0) ? Cq : (z == 1) ? Ck : Cv;

  const int t = threadIdx.x;
  const int lane = t & 63;
  const int w = t >> 6;
  const int wr = w >> 1, wc = w & 1;
  const int bxr = blockIdx.x;
  const int mt = (bxr & 7) * 16 + (bxr >> 3);
  const int bm = mt * 128;
  const int bn = blockIdx.y * 128;
  const int r0 = t >> 4, seg = t & 15;

  f32x4 acc[4][4] = {};
  float4 ar[8];

  auto loadA = [&](int kc) {
#pragma unroll
    for (int p = 0; p < 8; ++p)
      ar[p] = *(const float4*)(A + (size_t)(bm + p * 16 + r0) * 512 + kc * 64 + seg * 4);
  };
  auto writeA = [&](int bufi) {
#pragma unroll
    for (int p = 0; p < 8; ++p) {
      bf16x4 o = {(bf16)ar[p].x, (bf16)ar[p].y, (bf16)ar[p].z, (bf16)ar[p].w};
      *(bf16x4*)&As[bufi][p * 16 + r0][seg * 4] = o;
    }
  };
  auto issueW = [&](int kc, int bufi) {
    const int n = t >> 3, sg8 = t & 7;
#pragma unroll
    for (int i = 0; i < 4; ++i)
      async16(Wz + (size_t)(bn + i * 32 + n) * 512 + kc * 64 + sg8 * 8,
              &WsL[bufi][(i * 32 + n) * 64 + sg8 * 8]);
  };

  loadA(0);
  WAVE_VM0();
  writeA(0);
  issueW(0, 0);
  loadA(1);
  asm volatile("s_waitcnt vmcnt(8) lgkmcnt(0)" ::: "memory");
  __builtin_amdgcn_s_barrier();
  __builtin_amdgcn_sched_barrier(0);

#pragma unroll
  for (int kc = 0; kc < 8; ++kc) {
    const int c = kc & 1;
    if (kc < 7) issueW(kc + 1, c ^ 1);
    const int arow = lane & 15, kq = (lane >> 4) * 8;
#pragma unroll
    for (int kk = 0; kk < 2; ++kk) {
      bf16x8 af[4], bfr[4];
#pragma unroll
      for (int mi = 0; mi < 4; ++mi)
        af[mi] = *(const bf16x8*)&As[c][wr * 64 + mi * 16 + arow][kk * 32 + kq];
#pragma unroll
      for (int ni = 0; ni < 4; ++ni) {
        int n = wc * 64 + ni * 16 + arow;
        bfr[ni] = *(const bf16x8*)&WsL[c][n * 64 + ((kk * 32 + kq) ^ ((n & 7) << 3))];
      }
#pragma unroll
      for (int mi = 0; mi < 4; ++mi)
#pragma unroll
        for (int ni = 0; ni < 4; ++ni)
          acc[mi][ni] = mfma16(af[mi], bfr[ni], acc[mi][ni]);
    }
    if (kc < 7) {
      asm volatile("s_waitcnt vmcnt(4)" ::: "memory");
      writeA(c ^ 1);
      if (kc < 6) {
        loadA(kc + 2);
        asm volatile("s_waitcnt vmcnt(8) lgkmcnt(0)" ::: "memory");
      } else {
        asm volatile("s_waitcnt vmcnt(0) lgkmcnt(0)" ::: "memory");
      }
      __builtin_amdgcn_s_barrier();
      __builtin_amdgcn_sched_barrier(0);
    }
  }

  const int row0 = (lane >> 4) * 4, col = lane & 15;
#pragma unroll
  for (int mi = 0; mi < 4; ++mi)
#pragma unroll
    for (int ni = 0; ni < 4; ++ni) {
      int cg = bn + wc * 64 + ni * 16 + col;
#pragma unroll
      for (int j = 0; j < 4; ++j) {
        int rg = bm + wr * 64 + mi * 16 + row0 + j;
        bf16 o = (bf16)acc[mi][ni][j];
        if (z == 0) {
          C[(size_t)rg * ND + cg] = o;
        } else if (z == 1) {
          C[(size_t)rg * ND + (cg ^ ((rg & 7) << 3))] = o;
        } else {
          int bb = rg >> 11, s = rg & 2047;
          int ss = (s & ~63) | ((s & 63) ^ ((cg & 7) << 3));
          C[(size_t)bb * (ND * NS) + (size_t)cg * NS + ss] = o;
        }
      }
    }
}

// ---- kernel 2: wave-specialized pipelined causal flash attention ----
// r11 bodies unchanged. 512 blocks (b=id&7, h=id>>8). Size-pairing fix:
// h0 sizes DESCEND with id, h1 sizes ASCEND, so blocks k and k+256 (same CU
// under round-robin) always sum to 16-17 tiles -> balanced makespan.
__launch_bounds__(512, 2)
__global__ void attn_kernel(const bf16* __restrict__ Qg,
                            const bf16* __restrict__ Kg,    // col-swizzled
                            const bf16* __restrict__ Vtg,   // V^T, s-swizzled
                            bf16* __restrict__ Pn,
                            float* __restrict__ Mp,
                            float* __restrict__ Lp) {
  __shared__ bf16 Ks[64][512];      // 64 KB
  __shared__ bf16 Vts[512][64];     // 64 KB
  __shared__ bf16 Sx[64][68];       // 8.5 KB  (k-half partial exchange)
  __shared__ bf16 Ps[2][64][76];    // 19 KB   (P dbuf)
  __shared__ float r_lds[2][64];
  __shared__ float l_lds[64];

  const int t = threadIdx.x;
  const int lane = t & 63;
  const int w = t >> 6;
  const int l31 = lane & 31, lhi = lane >> 5;
  const int wq = w & 3;
  const bool isQK = w < 4;
  const int qh = wq & 1, skh = wq >> 1;
  const int dofs = wq * 128;

  const int id = blockIdx.x;
  const int b = id & 7;
  const int h = id >> 8;
  const int qtb = (id >> 3) & 31;
  const int qt = h ? qtb : (31 - qtb);   // h0 descending, h1 ascending sizes
  const int q0 = qt * 64;
  const int nt = qt + 1, mid = (nt + 1) >> 1;
  const int t_begin = h ? mid : 0;
  const int t_end = h ? nt : mid;
  const int NT = t_end - t_begin;
  const int pidx = (h * 8 + b) * 32 + qt;

  const bf16* Qb = Qg + (size_t)b * NS * ND;
  const bf16* Kb = Kg + (size_t)b * NS * ND;
  const bf16* Vb = Vtg + (size_t)b * ND * NS;

  if (isQK) {
    // ================= producer: QK^T + online softmax =================
    const int ql = qh * 32 + l31;
    const int qg = q0 + ql;
    bf16x8 qf[16];
    float m_run = -1e30f, l_run = 0.0f;
    if (NT > 0) {
      const bf16* qrow = Qb + (size_t)qg * ND + skh * 256 + lhi * 8;
#pragma unroll
      for (int kc = 0; kc < 16; ++kc) qf[kc] = *(const bf16x8*)(qrow + kc * 16);
#pragma unroll
      for (int i = 0; i < 16; ++i)   // stage K(t_begin): own 16 rows
        async16(Kb + (size_t)(t_begin * 64 + wq * 16 + i) * ND + lane * 8,
                &Ks[wq * 16 + i][0]);
    }
    for (int s = 0; s <= NT; ++s) {
      const int it = t_begin + s;
      f32x16 s0 = {}, s1 = {};
      if (s < NT) WAVE_VM0();          // own K-DMA (and Q frags at s=0) landed
      BLK_BAR();                       // B0: all K rows visible; Ps/r published
      if (s < NT) {
        __builtin_amdgcn_s_setprio(1);
#pragma unroll
        for (int kc = 0; kc < 16; ++kc) {
          const int colk = (skh * 256 + kc * 16 + lhi * 8) ^ ((l31 & 7) << 3);
          bf16x8 kf0 = *(const bf16x8*)&Ks[l31][colk];
          bf16x8 kf1 = *(const bf16x8*)&Ks[32 + l31][colk];
          s0 = mfma32(kf0, qf[kc], s0);   // D[kv][q], col=lane=q
          s1 = mfma32(kf1, qf[kc], s1);
        }
        __builtin_amdgcn_s_setprio(0);
        if (skh) {                     // publish K-half partial (bf16)
#pragma unroll
          for (int jg = 0; jg < 4; ++jg) {
            bf16x4 a = {(bf16)s0[jg * 4 + 0], (bf16)s0[jg * 4 + 1],
                        (bf16)s0[jg * 4 + 2], (bf16)s0[jg * 4 + 3]};
            bf16x4 c = {(bf16)s1[jg * 4 + 0], (bf16)s1[jg * 4 + 1],
                        (bf16)s1[jg * 4 + 2], (bf16)s1[jg * 4 + 3]};
            *(bf16x4*)&Sx[ql][jg * 8 + 4 * lhi] = a;
            *(bf16x4*)&Sx[ql][32 + jg * 8 + 4 * lhi] = c;
          }
        }
      }
      BLK_BAR();                       // B1: Sx visible; all Ks reads retired
      if (s < NT) {
        if (it + 1 < t_end) {          // prefetch next K
#pragma unroll
          for (int i = 0; i < 16; ++i)
            async16(Kb + (size_t)((it + 1) * 64 + wq * 16 + i) * ND + lane * 8,
                    &Ks[wq * 16 + i][0]);
        }
        if (!skh) {                    // combine + mask + softmax + publish P,r
          float v[32];
#pragma unroll
          for (int jg = 0; jg < 4; ++jg) {
            bf16x4 a = *(const bf16x4*)&Sx[ql][jg * 8 + 4 * lhi];
            bf16x4 c = *(const bf16x4*)&Sx[ql][32 + jg * 8 + 4 * lhi];
#pragma unroll
            for (int e = 0; e < 4; ++e) {
              v[jg * 4 + e] = s0[jg * 4 + e] + (float)a[e];
              v[16 + jg * 4 + e] = s1[jg * 4 + e] + (float)c[e];
            }
          }
          if (it == qt) {
            const int k0 = it * 64;
#pragma unroll
            for (int j = 0; j < 16; ++j) {
              int kv = k0 + (j & 3) + 8 * (j >> 2) + 4 * lhi;
              if (kv > qg) v[j] = -1e30f;
              if (kv + 32 > qg) v[16 + j] = -1e30f;
            }
          }
          float mx = v[0];
#pragma unroll
          for (int j = 1; j < 32; ++j) mx = fmaxf(mx, v[j]);
          mx = fmaxf(mx, __shfl_xor(mx, 32));
          float mn = fmaxf(m_run, mx);
          float rr = exp2f(m_run - mn);
          float sum = 0.0f;
#pragma unroll
          for (int j = 0; j < 32; ++j) { v[j] = exp2f(v[j] - mn); sum += v[j]; }
          sum += __shfl_xor(sum, 32);
          m_run = mn;
          l_run = l_run * rr + sum;
          if (lhi == 0) r_lds[it & 1][ql] = rr;
#pragma unroll
          for (int jg = 0; jg < 4; ++jg) {
            bf16x4 a = {(bf16)v[jg * 4 + 0], (bf16)v[jg * 4 + 1],
                        (bf16)v[jg * 4 + 2], (bf16)v[jg * 4 + 3]};
            bf16x4 c = {(bf16)v[16 + jg * 4 + 0], (bf16)v[16 + jg * 4 + 1],
                        (bf16)v[16 + jg * 4 + 2], (bf16)v[16 + jg * 4 + 3]};
            *(bf16x4*)&Ps[it & 1][ql][jg * 8 + 4 * lhi] = a;
            *(bf16x4*)&Ps[it & 1][ql][32 + jg * 8 + 4 * lhi] = c;
          }
        }
      }
    }
    if (!skh && lhi == 0) {
      Mp[pidx * 64 + ql] = m_run;
      Lp[pidx * 64 + ql] = l_run;
      l_lds[ql] = l_run;
    }
    BLK_BAR();                         // final: l_lds visible to PV
  } else {
    // ================= consumer: PV =================
    f32x16 acc[2][4] = {};
    if (NT > 0) {
#pragma unroll
      for (int i = 0; i < 16; ++i) {   // stage V(t_begin): own 128 d-rows
        int d = dofs + i * 8 + (lane >> 3);
        async16(Vb + (size_t)d * NS + t_begin * 64 + (lane & 7) * 8,
                &Vts[dofs + i * 8][0]);
      }
    }
    for (int s = 0; s <= NT; ++s) {
      const int it = t_begin + s;
      if (s >= 1) WAVE_VM0();          // own V-DMA landed
      BLK_BAR();                       // B0
      bf16x8 paf[2][4];
      if (s >= 1) {
        const int bb = (it - 1) & 1;
#pragma unroll
        for (int qb = 0; qb < 2; ++qb)
#pragma unroll
          for (int j = 0; j < 16; ++j) {
            float rr = r_lds[bb][qb * 32 + (j & 3) + 8 * (j >> 2) + 4 * lhi];
#pragma unroll
            for (int dt = 0; dt < 4; ++dt) acc[qb][dt][j] *= rr;
          }
#pragma unroll
        for (int qb = 0; qb < 2; ++qb)
#pragma unroll
          for (int kc = 0; kc < 4; ++kc)
            paf[qb][kc] = *(const bf16x8*)&Ps[bb][qb * 32 + l31][kc * 16 + lhi * 8];
        __builtin_amdgcn_s_setprio(1);
#pragma unroll
        for (int dt = 0; dt < 2; ++dt) {
          const int d = dofs + dt * 32 + l31;
          const int swzv = (d & 7) << 3;
#pragma unroll
          for (int kc = 0; kc < 4; ++kc) {
            bf16x8 vf = *(const bf16x8*)&Vts[d][(kc * 16 + lhi * 8) ^ swzv];
            acc[0][dt] = mfma32(paf[0][kc], vf, acc[0][dt]);
            acc[1][dt] = mfma32(paf[1][kc], vf, acc[1][dt]);
          }
        }
        __builtin_amdgcn_s_setprio(0);
      }
      BLK_BAR();                       // B1
      if (s >= 1) {
        __builtin_amdgcn_s_setprio(1);
#pragma unroll
        for (int dt = 2; dt < 4; ++dt) {
          const int d = dofs + dt * 32 + l31;
          const int swzv = (d & 7) << 3;
#pragma unroll
          for (int kc = 0; kc < 4; ++kc) {
            bf16x8 vf = *(const bf16x8*)&Vts[d][(kc * 16 + lhi * 8) ^ swzv];
            acc[0][dt] = mfma32(paf[0][kc], vf, acc[0][dt]);
            acc[1][dt] = mfma32(paf[1][kc], vf, acc[1][dt]);
          }
        }
        __builtin_amdgcn_s_setprio(0);
        asm volatile("s_waitcnt lgkmcnt(0)" ::: "memory");  // Vts reads retired
        if (it < t_end) {              // stage V(it) for next step
#pragma unroll
          for (int i = 0; i < 16; ++i) {
            int d = dofs + i * 8 + (lane >> 3);
            async16(Vb + (size_t)d * NS + it * 64 + (lane & 7) * 8,
                    &Vts[dofs + i * 8][0]);
          }
        }
      }
    }
    BLK_BAR();                         // final: wait l_lds
    // epilogue: normalized bf16 partial, own 128 d, all 64 q
    bf16* Ob = Pn + (size_t)pidx * 64 * ND;
#pragma unroll
    for (int qb = 0; qb < 2; ++qb)
#pragma unroll
      for (int j = 0; j < 16; ++j) {
        const int row = qb * 32 + (j & 3) + 8 * (j >> 2) + 4 * lhi;
        float lv = l_lds[row];
        float linv = (lv > 0.0f) ? 1.0f / lv : 0.0f;
#pragma unroll
        for (int dt = 0; dt < 4; ++dt)
          Ob[(size_t)row * ND + dofs + dt * 32 + l31] = (bf16)(acc[qb][dt][j] * linv);
      }
  }
}

// ---- kernel 3: combine two KV-half partials ----
__global__ void combine_kernel(const bf16* __restrict__ Pn,
                               const float* __restrict__ Mp,
                               const float* __restrict__ Lp,
                               float* __restrict__ Out) {
  const int total = NB * NS * ND / 4;
  for (int v = blockIdx.x * 256 + threadIdx.x; v < total; v += gridDim.x * 256) {
    int e = v * 4;
    int d = e & 511;
    int s = (e >> 9) & 2047;
    int bb = e >> 20;
    int qt = s >> 6, r = s & 63;
    int p0 = (bb * 32 + qt) * 64 + r;
    int p1 = ((8 + bb) * 32 + qt) * 64 + r;
    float m0 = Mp[p0], l0 = Lp[p0], m1 = Mp[p1], l1 = Lp[p1];
    float M = fmaxf(m0, m1);
    float w0 = l0 * exp2f(m0 - M), w1 = l1 * exp2f(m1 - M);
    float inv = 1.0f / (w0 + w1);
    bf16x4 o0 = *(const bf16x4*)(Pn + (size_t)p0 * ND + d);
    bf16x4 o1 = *(const bf16x4*)(Pn + (size_t)p1 * ND + d);
    f32x4 o;
    o[0] = (w0 * (float)o0[0] + w1 * (float)o1[0]) * inv;
    o[1] = (w0 * (float)o0[1] + w1 * (float)o1[1]) * inv;
    o[2] = (w0 * (float)o0[2] + w1 * (float)o1[2]) * inv;
    o[3] = (w0 * (float)o0[3] + w1 * (float)o1[3]) * inv;
    __builtin_nontemporal_store(o, (f32x4*)(Out + e));
  }
}

extern "C" void kernel_launch(void* const* d_in, const int* in_sizes, int n_in,
                              void* d_out, int out_size, void* d_ws, size_t ws_size,
                              hipStream_t stream) {
  const float* Xk = (const float*)d_in[0];
  const float* Xv = (const float*)d_in[1];
  const float* Xq = (const float*)d_in[2];
  const float* Wq = (const float*)d_in[3];
  const float* Wk = (const float*)d_in[4];
  const float* Wv = (const float*)d_in[5];
  float* Out = (float*)d_out;

  char* ws = (char*)d_ws;
  bf16* Qb = (bf16*)(ws);                                    // 16 MB
  bf16* Kb = (bf16*)(ws + (size_t)16 * 1024 * 1024);         // 16 MB (swizzled)
  bf16* Vt = (bf16*)(ws + (size_t)32 * 1024 * 1024);         // 16 MB (transposed+swizzled)
  bf16* Wt = (bf16*)(ws + (size_t)48 * 1024 * 1024);         // 1.5 MB (pre-swizzled)
  bf16* Pn = (bf16*)(ws + (size_t)50 * 1024 * 1024);         // 32 MB partials
  float* Mp = (float*)(ws + (size_t)82 * 1024 * 1024);       // 128 KB
  float* Lp = (float*)(ws + (size_t)82 * 1024 * 1024 + 131072);

  wconv_kernel<<<dim3(8, 8, 3), 256, 0, stream>>>(Wq, Wk, Wv, Wt);
  proj_kernel<<<dim3(128, 4, 3), 256, 0, stream>>>(Xq, Xk, Xv, Wt, Qb, Kb, Vt);
  attn_kernel<<<512, 512, 0, stream>>>(Qb, Kb, Vt, Pn, Mp, Lp);
  combine_kernel<<<2048, 256, 0, stream>>>(Pn, Mp, Lp, Out);
}

// Round 15
// 147.047 us; speedup vs baseline: 1.1632x; 1.1632x over previous
//
#include <hip/hip_runtime.h>
#include <hip/hip_bf16.h>

typedef __bf16 bf16;
typedef __bf16 bf16x4 __attribute__((ext_vector_type(4)));
typedef __bf16 bf16x8 __attribute__((ext_vector_type(8)));
typedef float f32x4 __attribute__((ext_vector_type(4)));
typedef float f32x16 __attribute__((ext_vector_type(16)));

#define NB 8
#define NS 2048
#define ND 512

static __device__ __forceinline__ f32x4 mfma16(bf16x8 a, bf16x8 b, f32x4 c) {
  return __builtin_amdgcn_mfma_f32_16x16x32_bf16(a, b, c, 0, 0, 0);
}
static __device__ __forceinline__ f32x16 mfma32(bf16x8 a, bf16x8 b, f32x16 c) {
  return __builtin_amdgcn_mfma_f32_32x32x16_bf16(a, b, c, 0, 0, 0);
}
static __device__ __forceinline__ void async16(const bf16* g, bf16* l) {
  __builtin_amdgcn_global_load_lds((const __attribute__((address_space(1))) void*)g,
                                   (__attribute__((address_space(3))) void*)l, 16, 0, 0);
}

#define WAVE_VM0() asm volatile("s_waitcnt vmcnt(0)" ::: "memory")
#define BLK_BAR() do { asm volatile("s_waitcnt lgkmcnt(0)" ::: "memory"); \
  __builtin_amdgcn_s_barrier(); __builtin_amdgcn_sched_barrier(0); } while (0)

// ---- kernel 0: W[k][n] (f32) -> Wt[z][n][k^((n&7)<<3)] (bf16, pre-swizzled).
// Wq additionally scaled by rsqrt(512)*log2e (folds softmax scale into Q).
__global__ void wconv_kernel(const float* __restrict__ Wq,
                             const float* __restrict__ Wk,
                             const float* __restrict__ Wv,
                             bf16* __restrict__ Wt) {
  __shared__ float buf[64][65];
  const int z = blockIdx.z;
  const float* W = (z == 0) ? Wq : (z == 1) ? Wk : Wv;
  const float scale = (z == 0) ? 0.063763537f : 1.0f;
  const int k0 = blockIdx.x * 64, n0 = blockIdx.y * 64;
  const int t = threadIdx.x;
#pragma unroll
  for (int i = 0; i < 16; ++i) {
    int idx = i * 256 + t;
    int kk = idx >> 6, nn = idx & 63;
    buf[kk][nn] = W[(size_t)(k0 + kk) * 512 + n0 + nn];
  }
  __syncthreads();
#pragma unroll
  for (int i = 0; i < 16; ++i) {
    int idx = i * 256 + t;
    int nn = idx >> 6, kk = idx & 63;
    Wt[(size_t)z * 262144 + (size_t)(n0 + nn) * 512 + k0 + (kk ^ ((nn & 7) << 3))] =
        (bf16)(buf[kk][nn] * scale);
  }
}

// ---- kernel 1: fused 3x projection (round-11 proven) ----
__launch_bounds__(256)
__global__ void proj_kernel(const float* __restrict__ Xq,
                            const float* __restrict__ Xk,
                            const float* __restrict__ Xv,
                            const bf16* __restrict__ Wt,
                            bf16* __restrict__ Cq,
                            bf16* __restrict__ Ck,
                            bf16* __restrict__ Cv) {
  __shared__ bf16 As[2][128][72];
  __shared__ bf16 WsL[2][8192];
  const int z = blockIdx.z;
  const float* A = (z == 0) ? Xq : (z == 1) ? Xk : Xv;
  const bf16* Wz = Wt + (size_t)z * 262144;
  bf16* C = (z == 0) ? Cq : (z == 1) ? Ck : Cv;

  const int t = threadIdx.x;
  const int lane = t & 63;
  const int w = t >> 6;
  const int wr = w >> 1, wc = w & 1;
  const int bxr = blockIdx.x;
  const int mt = (bxr & 7) * 16 + (bxr >> 3);
  const int bm = mt * 128;
  const int bn = blockIdx.y * 128;
  const int r0 = t >> 4, seg = t & 15;

  f32x4 acc[4][4] = {};
  float4 ar[8];

  auto loadA = [&](int kc) {
#pragma unroll
    for (int p = 0; p < 8; ++p)
      ar[p] = *(const float4*)(A + (size_t)(bm + p * 16 + r0) * 512 + kc * 64 + seg * 4);
  };
  auto writeA = [&](int bufi) {
#pragma unroll
    for (int p = 0; p < 8; ++p) {
      bf16x4 o = {(bf16)ar[p].x, (bf16)ar[p].y, (bf16)ar[p].z, (bf16)ar[p].w};
      *(bf16x4*)&As[bufi][p * 16 + r0][seg * 4] = o;
    }
  };
  auto issueW = [&](int kc, int bufi) {
    const int n = t >> 3, sg8 = t & 7;
#pragma unroll
    for (int i = 0; i < 4; ++i)
      async16(Wz + (size_t)(bn + i * 32 + n) * 512 + kc * 64 + sg8 * 8,
              &WsL[bufi][(i * 32 + n) * 64 + sg8 * 8]);
  };

  loadA(0);
  WAVE_VM0();
  writeA(0);
  issueW(0, 0);
  loadA(1);
  asm volatile("s_waitcnt vmcnt(8) lgkmcnt(0)" ::: "memory");
  __builtin_amdgcn_s_barrier();
  __builtin_amdgcn_sched_barrier(0);

#pragma unroll
  for (int kc = 0; kc < 8; ++kc) {
    const int c = kc & 1;
    if (kc < 7) issueW(kc + 1, c ^ 1);
    const int arow = lane & 15, kq = (lane >> 4) * 8;
#pragma unroll
    for (int kk = 0; kk < 2; ++kk) {
      bf16x8 af[4], bfr[4];
#pragma unroll
      for (int mi = 0; mi < 4; ++mi)
        af[mi] = *(const bf16x8*)&As[c][wr * 64 + mi * 16 + arow][kk * 32 + kq];
#pragma unroll
      for (int ni = 0; ni < 4; ++ni) {
        int n = wc * 64 + ni * 16 + arow;
        bfr[ni] = *(const bf16x8*)&WsL[c][n * 64 + ((kk * 32 + kq) ^ ((n & 7) << 3))];
      }
#pragma unroll
      for (int mi = 0; mi < 4; ++mi)
#pragma unroll
        for (int ni = 0; ni < 4; ++ni)
          acc[mi][ni] = mfma16(af[mi], bfr[ni], acc[mi][ni]);
    }
    if (kc < 7) {
      asm volatile("s_waitcnt vmcnt(4)" ::: "memory");
      writeA(c ^ 1);
      if (kc < 6) {
        loadA(kc + 2);
        asm volatile("s_waitcnt vmcnt(8) lgkmcnt(0)" ::: "memory");
      } else {
        asm volatile("s_waitcnt vmcnt(0) lgkmcnt(0)" ::: "memory");
      }
      __builtin_amdgcn_s_barrier();
      __builtin_amdgcn_sched_barrier(0);
    }
  }

  const int row0 = (lane >> 4) * 4, col = lane & 15;
#pragma unroll
  for (int mi = 0; mi < 4; ++mi)
#pragma unroll
    for (int ni = 0; ni < 4; ++ni) {
      int cg = bn + wc * 64 + ni * 16 + col;
#pragma unroll
      for (int j = 0; j < 4; ++j) {
        int rg = bm + wr * 64 + mi * 16 + row0 + j;
        bf16 o = (bf16)acc[mi][ni][j];
        if (z == 0) {
          C[(size_t)rg * ND + cg] = o;
        } else if (z == 1) {
          C[(size_t)rg * ND + (cg ^ ((rg & 7) << 3))] = o;
        } else {
          int bb = rg >> 11, s = rg & 2047;
          int ss = (s & ~63) | ((s & 63) ^ ((cg & 7) << 3));
          C[(size_t)bb * (ND * NS) + (size_t)cg * NS + ss] = o;
        }
      }
    }
}

// ---- kernel 2: wave-specialized pipelined causal flash attention ----
// Round-11 proven configuration (146.6us total, attn 78us).
// 512 blocks (b=id&7 XCD pin, qt descending, h=id>>8 KV-half), 8 waves.
// Waves 0-3 = QK producers (qh=w&1 q-half, skh=w>>1 K-half; swapped mfma32(K,Q),
// bf16 Sx k-half exchange, in-register online softmax -> Ps/r dbuf).
// Waves 4-7 = PV consumers (each owns 128 d; reads Ps[(it-1)&1], V self-staged).
__launch_bounds__(512, 2)
__global__ void attn_kernel(const bf16* __restrict__ Qg,
                            const bf16* __restrict__ Kg,    // col-swizzled
                            const bf16* __restrict__ Vtg,   // V^T, s-swizzled
                            bf16* __restrict__ Pn,
                            float* __restrict__ Mp,
                            float* __restrict__ Lp) {
  __shared__ bf16 Ks[64][512];      // 64 KB
  __shared__ bf16 Vts[512][64];     // 64 KB
  __shared__ bf16 Sx[64][68];       // 8.5 KB  (k-half partial exchange)
  __shared__ bf16 Ps[2][64][76];    // 19 KB   (P dbuf)
  __shared__ float r_lds[2][64];
  __shared__ float l_lds[64];

  const int t = threadIdx.x;
  const int lane = t & 63;
  const int w = t >> 6;
  const int l31 = lane & 31, lhi = lane >> 5;
  const int wq = w & 3;
  const bool isQK = w < 4;
  const int qh = wq & 1, skh = wq >> 1;
  const int dofs = wq * 128;

  const int id = blockIdx.x;
  const int b = id & 7;
  const int qt = 31 - ((id >> 3) & 31);
  const int h = id >> 8;
  const int q0 = qt * 64;
  const int nt = qt + 1, mid = (nt + 1) >> 1;
  const int t_begin = h ? mid : 0;
  const int t_end = h ? nt : mid;
  const int NT = t_end - t_begin;
  const int pidx = (h * 8 + b) * 32 + qt;

  const bf16* Qb = Qg + (size_t)b * NS * ND;
  const bf16* Kb = Kg + (size_t)b * NS * ND;
  const bf16* Vb = Vtg + (size_t)b * ND * NS;

  if (isQK) {
    // ================= producer: QK^T + online softmax =================
    const int ql = qh * 32 + l31;
    const int qg = q0 + ql;
    bf16x8 qf[16];
    float m_run = -1e30f, l_run = 0.0f;
    if (NT > 0) {
      const bf16* qrow = Qb + (size_t)qg * ND + skh * 256 + lhi * 8;
#pragma unroll
      for (int kc = 0; kc < 16; ++kc) qf[kc] = *(const bf16x8*)(qrow + kc * 16);
#pragma unroll
      for (int i = 0; i < 16; ++i)   // stage K(t_begin): own 16 rows
        async16(Kb + (size_t)(t_begin * 64 + wq * 16 + i) * ND + lane * 8,
                &Ks[wq * 16 + i][0]);
    }
    for (int s = 0; s <= NT; ++s) {
      const int it = t_begin + s;
      f32x16 s0 = {}, s1 = {};
      if (s < NT) WAVE_VM0();          // own K-DMA (and Q frags at s=0) landed
      BLK_BAR();                       // B0: all K rows visible; Ps/r published
      if (s < NT) {
        __builtin_amdgcn_s_setprio(1);
#pragma unroll
        for (int kc = 0; kc < 16; ++kc) {
          const int colk = (skh * 256 + kc * 16 + lhi * 8) ^ ((l31 & 7) << 3);
          bf16x8 kf0 = *(const bf16x8*)&Ks[l31][colk];
          bf16x8 kf1 = *(const bf16x8*)&Ks[32 + l31][colk];
          s0 = mfma32(kf0, qf[kc], s0);   // D[kv][q], col=lane=q
          s1 = mfma32(kf1, qf[kc], s1);
        }
        __builtin_amdgcn_s_setprio(0);
        if (skh) {                     // publish K-half partial (bf16)
#pragma unroll
          for (int jg = 0; jg < 4; ++jg) {
            bf16x4 a = {(bf16)s0[jg * 4 + 0], (bf16)s0[jg * 4 + 1],
                        (bf16)s0[jg * 4 + 2], (bf16)s0[jg * 4 + 3]};
            bf16x4 c = {(bf16)s1[jg * 4 + 0], (bf16)s1[jg * 4 + 1],
                        (bf16)s1[jg * 4 + 2], (bf16)s1[jg * 4 + 3]};
            *(bf16x4*)&Sx[ql][jg * 8 + 4 * lhi] = a;
            *(bf16x4*)&Sx[ql][32 + jg * 8 + 4 * lhi] = c;
          }
        }
      }
      BLK_BAR();                       // B1: Sx visible; all Ks reads retired
      if (s < NT) {
        if (it + 1 < t_end) {          // prefetch next K
#pragma unroll
          for (int i = 0; i < 16; ++i)
            async16(Kb + (size_t)((it + 1) * 64 + wq * 16 + i) * ND + lane * 8,
                    &Ks[wq * 16 + i][0]);
        }
        if (!skh) {                    // combine + mask + softmax + publish P,r
          float v[32];
#pragma unroll
          for (int jg = 0; jg < 4; ++jg) {
            bf16x4 a = *(const bf16x4*)&Sx[ql][jg * 8 + 4 * lhi];
            bf16x4 c = *(const bf16x4*)&Sx[ql][32 + jg * 8 + 4 * lhi];
#pragma unroll
            for (int e = 0; e < 4; ++e) {
              v[jg * 4 + e] = s0[jg * 4 + e] + (float)a[e];
              v[16 + jg * 4 + e] = s1[jg * 4 + e] + (float)c[e];
            }
          }
          if (it == qt) {
            const int k0 = it * 64;
#pragma unroll
            for (int j = 0; j < 16; ++j) {
              int kv = k0 + (j & 3) + 8 * (j >> 2) + 4 * lhi;
              if (kv > qg) v[j] = -1e30f;
              if (kv + 32 > qg) v[16 + j] = -1e30f;
            }
          }
          float mx = v[0];
#pragma unroll
          for (int j = 1; j < 32; ++j) mx = fmaxf(mx, v[j]);
          mx = fmaxf(mx, __shfl_xor(mx, 32));
          float mn = fmaxf(m_run, mx);
          float rr = exp2f(m_run - mn);
          float sum = 0.0f;
#pragma unroll
          for (int j = 0; j < 32; ++j) { v[j] = exp2f(v[j] - mn); sum += v[j]; }
          sum += __shfl_xor(sum, 32);
          m_run = mn;
          l_run = l_run * rr + sum;
          if (lhi == 0) r_lds[it & 1][ql] = rr;
#pragma unroll
          for (int jg = 0; jg < 4; ++jg) {
            bf16x4 a = {(bf16)v[jg * 4 + 0], (bf16)v[jg * 4 + 1],
                        (bf16)v[jg * 4 + 2], (bf16)v[jg * 4 + 3]};
            bf16x4 c = {(bf16)v[16 + jg * 4 + 0], (bf16)v[16 + jg * 4 + 1],
                        (bf16)v[16 + jg * 4 + 2], (bf16)v[16 + jg * 4 + 3]};
            *(bf16x4*)&Ps[it & 1][ql][jg * 8 + 4 * lhi] = a;
            *(bf16x4*)&Ps[it & 1][ql][32 + jg * 8 + 4 * lhi] = c;
          }
        }
      }
    }
    if (!skh && lhi == 0) {
      Mp[pidx * 64 + ql] = m_run;
      Lp[pidx * 64 + ql] = l_run;
      l_lds[ql] = l_run;
    }
    BLK_BAR();                         // final: l_lds visible to PV
  } else {
    // ================= consumer: PV =================
    f32x16 acc[2][4] = {};
    if (NT > 0) {
#pragma unroll
      for (int i = 0; i < 16; ++i) {   // stage V(t_begin): own 128 d-rows
        int d = dofs + i * 8 + (lane >> 3);
        async16(Vb + (size_t)d * NS + t_begin * 64 + (lane & 7) * 8,
                &Vts[dofs + i * 8][0]);
      }
    }
    for (int s = 0; s <= NT; ++s) {
      const int it = t_begin + s;
      if (s >= 1) WAVE_VM0();          // own V-DMA landed
      BLK_BAR();                       // B0
      bf16x8 paf[2][4];
      if (s >= 1) {
        const int bb = (it - 1) & 1;
#pragma unroll
        for (int qb = 0; qb < 2; ++qb)
#pragma unroll
          for (int j = 0; j < 16; ++j) {
            float rr = r_lds[bb][qb * 32 + (j & 3) + 8 * (j >> 2) + 4 * lhi];
#pragma unroll
            for (int dt = 0; dt < 4; ++dt) acc[qb][dt][j] *= rr;
          }
#pragma unroll
        for (int qb = 0; qb < 2; ++qb)
#pragma unroll
          for (int kc = 0; kc < 4; ++kc)
            paf[qb][kc] = *(const bf16x8*)&Ps[bb][qb * 32 + l31][kc * 16 + lhi * 8];
        __builtin_amdgcn_s_setprio(1);
#pragma unroll
        for (int dt = 0; dt < 2; ++dt) {
          const int d = dofs + dt * 32 + l31;
          const int swzv = (d & 7) << 3;
#pragma unroll
          for (int kc = 0; kc < 4; ++kc) {
            bf16x8 vf = *(const bf16x8*)&Vts[d][(kc * 16 + lhi * 8) ^ swzv];
            acc[0][dt] = mfma32(paf[0][kc], vf, acc[0][dt]);
            acc[1][dt] = mfma32(paf[1][kc], vf, acc[1][dt]);
          }
        }
        __builtin_amdgcn_s_setprio(0);
      }
      BLK_BAR();                       // B1
      if (s >= 1) {
        __builtin_amdgcn_s_setprio(1);
#pragma unroll
        for (int dt = 2; dt < 4; ++dt) {
          const int d = dofs + dt * 32 + l31;
          const int swzv = (d & 7) << 3;
#pragma unroll
          for (int kc = 0; kc < 4; ++kc) {
            bf16x8 vf = *(const bf16x8*)&Vts[d][(kc * 16 + lhi * 8) ^ swzv];
            acc[0][dt] = mfma32(paf[0][kc], vf, acc[0][dt]);
            acc[1][dt] = mfma32(paf[1][kc], vf, acc[1][dt]);
          }
        }
        __builtin_amdgcn_s_setprio(0);
        asm volatile("s_waitcnt lgkmcnt(0)" ::: "memory");  // Vts reads retired
        if (it < t_end) {              // stage V(it) for next step
#pragma unroll
          for (int i = 0; i < 16; ++i) {
            int d = dofs + i * 8 + (lane >> 3);
            async16(Vb + (size_t)d * NS + it * 64 + (lane & 7) * 8,
                    &Vts[dofs + i * 8][0]);
          }
        }
      }
    }
    BLK_BAR();                         // final: wait l_lds
    // epilogue: normalized bf16 partial, own 128 d, all 64 q
    bf16* Ob = Pn + (size_t)pidx * 64 * ND;
#pragma unroll
    for (int qb = 0; qb < 2; ++qb)
#pragma unroll
      for (int j = 0; j < 16; ++j) {
        const int row = qb * 32 + (j & 3) + 8 * (j >> 2) + 4 * lhi;
        float lv = l_lds[row];
        float linv = (lv > 0.0f) ? 1.0f / lv : 0.0f;
#pragma unroll
        for (int dt = 0; dt < 4; ++dt)
          Ob[(size_t)row * ND + dofs + dt * 32 + l31] = (bf16)(acc[qb][dt][j] * linv);
      }
  }
}

// ---- kernel 3: combine two KV-half partials ----
__global__ void combine_kernel(const bf16* __restrict__ Pn,
                               const float* __restrict__ Mp,
                               const float* __restrict__ Lp,
                               float* __restrict__ Out) {
  const int total = NB * NS * ND / 4;
  for (int v = blockIdx.x * 256 + threadIdx.x; v < total; v += gridDim.x * 256) {
    int e = v * 4;
    int d = e & 511;
    int s = (e >> 9) & 2047;
    int bb = e >> 20;
    int qt = s >> 6, r = s & 63;
    int p0 = (bb * 32 + qt) * 64 + r;
    int p1 = ((8 + bb) * 32 + qt) * 64 + r;
    float m0 = Mp[p0], l0 = Lp[p0], m1 = Mp[p1], l1 = Lp[p1];
    float M = fmaxf(m0, m1);
    float w0 = l0 * exp2f(m0 - M), w1 = l1 * exp2f(m1 - M);
    float inv = 1.0f / (w0 + w1);
    bf16x4 o0 = *(const bf16x4*)(Pn + (size_t)p0 * ND + d);
    bf16x4 o1 = *(const bf16x4*)(Pn + (size_t)p1 * ND + d);
    f32x4 o;
    o[0] = (w0 * (float)o0[0] + w1 * (float)o1[0]) * inv;
    o[1] = (w0 * (float)o0[1] + w1 * (float)o1[1]) * inv;
    o[2] = (w0 * (float)o0[2] + w1 * (float)o1[2]) * inv;
    o[3] = (w0 * (float)o0[3] + w1 * (float)o1[3]) * inv;
    __builtin_nontemporal_store(o, (f32x4*)(Out + e));
  }
}

extern "C" void kernel_launch(void* const* d_in, const int* in_sizes, int n_in,
                              void* d_out, int out_size, void* d_ws, size_t ws_size,
                              hipStream_t stream) {
  const float* Xk = (const float*)d_in[0];
  const float* Xv = (const float*)d_in[1];
  const float* Xq = (const float*)d_in[2];
  const float* Wq = (const float*)d_in[3];
  const float* Wk = (const float*)d_in[4];
  const float* Wv = (const float*)d_in[5];
  float* Out = (float*)d_out;

  char* ws = (char*)d_ws;
  bf16* Qb = (bf16*)(ws);                                    // 16 MB
  bf16* Kb = (bf16*)(ws + (size_t)16 * 1024 * 1024);         // 16 MB (swizzled)
  bf16* Vt = (bf16*)(ws + (size_t)32 * 1024 * 1024);         // 16 MB (transposed+swizzled)
  bf16* Wt = (bf16*)(ws + (size_t)48 * 1024 * 1024);         // 1.5 MB (pre-swizzled)
  bf16* Pn = (bf16*)(ws + (size_t)50 * 1024 * 1024);         // 32 MB partials
  float* Mp = (float*)(ws + (size_t)82 * 1024 * 1024);       // 128 KB
  float* Lp = (float*)(ws + (size_t)82 * 1024 * 1024 + 131072);

  wconv_kernel<<<dim3(8, 8, 3), 256, 0, stream>>>(Wq, Wk, Wv, Wt);
  proj_kernel<<<dim3(128, 4, 3), 256, 0, stream>>>(Xq, Xk, Xv, Wt, Qb, Kb, Vt);
  attn_kernel<<<512, 512, 0, stream>>>(Qb, Kb, Vt, Pn, Mp, Lp);
  combine_kernel<<<2048, 256, 0, stream>>>(Pn, Mp, Lp, Out);
}

// Round 16
// 145.726 us; speedup vs baseline: 1.1738x; 1.0091x over previous
//
#include <hip/hip_runtime.h>
#include <hip/hip_bf16.h>

typedef __bf16 bf16;
typedef __bf16 bf16x4 __attribute__((ext_vector_type(4)));
typedef __bf16 bf16x8 __attribute__((ext_vector_type(8)));
typedef float f32x4 __attribute__((ext_vector_type(4)));
typedef float f32x16 __attribute__((ext_vector_type(16)));

#define NB 8
#define NS 2048
#define ND 512

static __device__ __forceinline__ f32x4 mfma16(bf16x8 a, bf16x8 b, f32x4 c) {
  return __builtin_amdgcn_mfma_f32_16x16x32_bf16(a, b, c, 0, 0, 0);
}
static __device__ __forceinline__ f32x16 mfma32(bf16x8 a, bf16x8 b, f32x16 c) {
  return __builtin_amdgcn_mfma_f32_32x32x16_bf16(a, b, c, 0, 0, 0);
}
static __device__ __forceinline__ void async16(const bf16* g, bf16* l) {
  __builtin_amdgcn_global_load_lds((const __attribute__((address_space(1))) void*)g,
                                   (__attribute__((address_space(3))) void*)l, 16, 0, 0);
}

#define WAVE_VM0() asm volatile("s_waitcnt vmcnt(0)" ::: "memory")
#define BLK_BAR() do { asm volatile("s_waitcnt lgkmcnt(0)" ::: "memory"); \
  __builtin_amdgcn_s_barrier(); __builtin_amdgcn_sched_barrier(0); } while (0)

// ---- kernel 0: W[k][n] (f32) -> Wt[z][n][k^((n&7)<<3)] (bf16, pre-swizzled).
// Wq additionally scaled by rsqrt(512)*log2e (folds softmax scale into Q).
__global__ void wconv_kernel(const float* __restrict__ Wq,
                             const float* __restrict__ Wk,
                             const float* __restrict__ Wv,
                             bf16* __restrict__ Wt) {
  __shared__ float buf[64][65];
  const int z = blockIdx.z;
  const float* W = (z == 0) ? Wq : (z == 1) ? Wk : Wv;
  const float scale = (z == 0) ? 0.063763537f : 1.0f;
  const int k0 = blockIdx.x * 64, n0 = blockIdx.y * 64;
  const int t = threadIdx.x;
#pragma unroll
  for (int i = 0; i < 16; ++i) {
    int idx = i * 256 + t;
    int kk = idx >> 6, nn = idx & 63;
    buf[kk][nn] = W[(size_t)(k0 + kk) * 512 + n0 + nn];
  }
  __syncthreads();
#pragma unroll
  for (int i = 0; i < 16; ++i) {
    int idx = i * 256 + t;
    int nn = idx >> 6, kk = idx & 63;
    Wt[(size_t)z * 262144 + (size_t)(n0 + nn) * 512 + k0 + (kk ^ ((nn & 7) << 3))] =
        (bf16)(buf[kk][nn] * scale);
  }
}

// ---- kernel 1: fused 3x projection, 128x256 tiles ----
// Reg-staged A pipeline + W global_load_lds with counted vmcnt (r11 structure,
// counts re-derived for 4 A-loads / 4 W-DMA per thread). 8 waves (2M x 4N).
// z=0: Q plain; z=1: K col-swizzled; z=2: V^T [B][512][2048] s-swizzled.
__launch_bounds__(512)
__global__ void proj_kernel(const float* __restrict__ Xq,
                            const float* __restrict__ Xk,
                            const float* __restrict__ Xv,
                            const bf16* __restrict__ Wt,
                            bf16* __restrict__ Cq,
                            bf16* __restrict__ Ck,
                            bf16* __restrict__ Cv) {
  __shared__ bf16 As[2][128][72];     // 36 KB
  __shared__ bf16 WsL[2][16384];      // 64 KB: [256 n][64 k] linear (DMA dest)
  const int z = blockIdx.z;
  const float* A = (z == 0) ? Xq : (z == 1) ? Xk : Xv;
  const bf16* Wz = Wt + (size_t)z * 262144;
  bf16* C = (z == 0) ? Cq : (z == 1) ? Ck : Cv;

  const int t = threadIdx.x;
  const int lane = t & 63;
  const int w = t >> 6;
  const int wr = w >> 2, wc = w & 3;            // 2 x 4 waves, 64x64 each
  const int bxr = blockIdx.x;
  const int mt = (bxr & 7) * 16 + (bxr >> 3);   // batch-pinned M-tile
  const int bm = mt * 128;
  const int bn = blockIdx.y * 256;
  const int r0 = t >> 4, seg = t & 15;          // r0 in [0,32)

  f32x4 acc[4][4] = {};
  float4 ar[4];                                 // A prefetch regs (static idx)

  auto loadA = [&](int kc) {
#pragma unroll
    for (int p = 0; p < 4; ++p)
      ar[p] = *(const float4*)(A + (size_t)(bm + p * 32 + r0) * 512 + kc * 64 + seg * 4);
  };
  auto writeA = [&](int bufi) {
#pragma unroll
    for (int p = 0; p < 4; ++p) {
      bf16x4 o = {(bf16)ar[p].x, (bf16)ar[p].y, (bf16)ar[p].z, (bf16)ar[p].w};
      *(bf16x4*)&As[bufi][p * 32 + r0][seg * 4] = o;
    }
  };
  // W DMA: stripe i covers rows i*64 + (t>>3), chunk (t&7)*8 -> LDS offset
  // i*4096 + t*8 bf16 (linear in t x 16B: rule-21 compliant).
  auto issueW = [&](int kc, int bufi) {
    const int n8 = t >> 3, sg8 = t & 7;
#pragma unroll
    for (int i = 0; i < 4; ++i)
      async16(Wz + (size_t)(bn + i * 64 + n8) * 512 + kc * 64 + sg8 * 8,
              &WsL[bufi][i * 4096 + t * 8]);
  };

  // prologue: A0 -> regs -> LDS; W0 DMA; A1 in flight across the barrier
  loadA(0);
  WAVE_VM0();
  writeA(0);
  issueW(0, 0);                     // queue: W0(4)
  loadA(1);                         // queue: W0(4), A1(4)
  asm volatile("s_waitcnt vmcnt(4) lgkmcnt(0)" ::: "memory");   // W0 landed
  __builtin_amdgcn_s_barrier();
  __builtin_amdgcn_sched_barrier(0);

#pragma unroll
  for (int kc = 0; kc < 8; ++kc) {
    const int c = kc & 1;
    if (kc < 7) issueW(kc + 1, c ^ 1);   // queue: A(kc+1)(4) + W(kc+1)(4)
    const int arow = lane & 15, kq = (lane >> 4) * 8;
#pragma unroll
    for (int kk = 0; kk < 2; ++kk) {
      bf16x8 af[4], bfr[4];
#pragma unroll
      for (int mi = 0; mi < 4; ++mi)
        af[mi] = *(const bf16x8*)&As[c][wr * 64 + mi * 16 + arow][kk * 32 + kq];
#pragma unroll
      for (int ni = 0; ni < 4; ++ni) {
        int n = wc * 64 + ni * 16 + arow;
        bfr[ni] = *(const bf16x8*)&WsL[c][n * 64 + ((kk * 32 + kq) ^ ((n & 7) << 3))];
      }
#pragma unroll
      for (int mi = 0; mi < 4; ++mi)
#pragma unroll
        for (int ni = 0; ni < 4; ++ni)
          acc[mi][ni] = mfma16(af[mi], bfr[ni], acc[mi][ni]);
    }
    if (kc < 7) {
      asm volatile("s_waitcnt vmcnt(4)" ::: "memory");   // A(kc+1) landed
      writeA(c ^ 1);
      if (kc < 6) {
        loadA(kc + 2);               // queue: W(kc+1)(4) + A(kc+2)(4)
        asm volatile("s_waitcnt vmcnt(4) lgkmcnt(0)" ::: "memory");  // W landed
      } else {
        asm volatile("s_waitcnt vmcnt(0) lgkmcnt(0)" ::: "memory");
      }
      __builtin_amdgcn_s_barrier();
      __builtin_amdgcn_sched_barrier(0);
    }
  }

  const int row0 = (lane >> 4) * 4, col = lane & 15;
#pragma unroll
  for (int mi = 0; mi < 4; ++mi)
#pragma unroll
    for (int ni = 0; ni < 4; ++ni) {
      int cg = bn + wc * 64 + ni * 16 + col;
#pragma unroll
      for (int j = 0; j < 4; ++j) {
        int rg = bm + wr * 64 + mi * 16 + row0 + j;
        bf16 o = (bf16)acc[mi][ni][j];
        if (z == 0) {
          C[(size_t)rg * ND + cg] = o;
        } else if (z == 1) {
          C[(size_t)rg * ND + (cg ^ ((rg & 7) << 3))] = o;
        } else {
          int bb = rg >> 11, s = rg & 2047;
          int ss = (s & ~63) | ((s & 63) ^ ((cg & 7) << 3));
          C[(size_t)bb * (ND * NS) + (size_t)cg * NS + ss] = o;
        }
      }
    }
}

// ---- kernel 2: wave-specialized pipelined causal flash attention ----
// Round-11 proven configuration (attn ~78us) — byte-identical.
__launch_bounds__(512, 2)
__global__ void attn_kernel(const bf16* __restrict__ Qg,
                            const bf16* __restrict__ Kg,    // col-swizzled
                            const bf16* __restrict__ Vtg,   // V^T, s-swizzled
                            bf16* __restrict__ Pn,
                            float* __restrict__ Mp,
                            float* __restrict__ Lp) {
  __shared__ bf16 Ks[64][512];      // 64 KB
  __shared__ bf16 Vts[512][64];     // 64 KB
  __shared__ bf16 Sx[64][68];       // 8.5 KB  (k-half partial exchange)
  __shared__ bf16 Ps[2][64][76];    // 19 KB   (P dbuf)
  __shared__ float r_lds[2][64];
  __shared__ float l_lds[64];

  const int t = threadIdx.x;
  const int lane = t & 63;
  const int w = t >> 6;
  const int l31 = lane & 31, lhi = lane >> 5;
  const int wq = w & 3;
  const bool isQK = w < 4;
  const int qh = wq & 1, skh = wq >> 1;
  const int dofs = wq * 128;

  const int id = blockIdx.x;
  const int b = id & 7;
  const int qt = 31 - ((id >> 3) & 31);
  const int h = id >> 8;
  const int q0 = qt * 64;
  const int nt = qt + 1, mid = (nt + 1) >> 1;
  const int t_begin = h ? mid : 0;
  const int t_end = h ? nt : mid;
  const int NT = t_end - t_begin;
  const int pidx = (h * 8 + b) * 32 + qt;

  const bf16* Qb = Qg + (size_t)b * NS * ND;
  const bf16* Kb = Kg + (size_t)b * NS * ND;
  const bf16* Vb = Vtg + (size_t)b * ND * NS;

  if (isQK) {
    // ================= producer: QK^T + online softmax =================
    const int ql = qh * 32 + l31;
    const int qg = q0 + ql;
    bf16x8 qf[16];
    float m_run = -1e30f, l_run = 0.0f;
    if (NT > 0) {
      const bf16* qrow = Qb + (size_t)qg * ND + skh * 256 + lhi * 8;
#pragma unroll
      for (int kc = 0; kc < 16; ++kc) qf[kc] = *(const bf16x8*)(qrow + kc * 16);
#pragma unroll
      for (int i = 0; i < 16; ++i)   // stage K(t_begin): own 16 rows
        async16(Kb + (size_t)(t_begin * 64 + wq * 16 + i) * ND + lane * 8,
                &Ks[wq * 16 + i][0]);
    }
    for (int s = 0; s <= NT; ++s) {
      const int it = t_begin + s;
      f32x16 s0 = {}, s1 = {};
      if (s < NT) WAVE_VM0();          // own K-DMA (and Q frags at s=0) landed
      BLK_BAR();                       // B0: all K rows visible; Ps/r published
      if (s < NT) {
        __builtin_amdgcn_s_setprio(1);
#pragma unroll
        for (int kc = 0; kc < 16; ++kc) {
          const int colk = (skh * 256 + kc * 16 + lhi * 8) ^ ((l31 & 7) << 3);
          bf16x8 kf0 = *(const bf16x8*)&Ks[l31][colk];
          bf16x8 kf1 = *(const bf16x8*)&Ks[32 + l31][colk];
          s0 = mfma32(kf0, qf[kc], s0);   // D[kv][q], col=lane=q
          s1 = mfma32(kf1, qf[kc], s1);
        }
        __builtin_amdgcn_s_setprio(0);
        if (skh) {                     // publish K-half partial (bf16)
#pragma unroll
          for (int jg = 0; jg < 4; ++jg) {
            bf16x4 a = {(bf16)s0[jg * 4 + 0], (bf16)s0[jg * 4 + 1],
                        (bf16)s0[jg * 4 + 2], (bf16)s0[jg * 4 + 3]};
            bf16x4 c = {(bf16)s1[jg * 4 + 0], (bf16)s1[jg * 4 + 1],
                        (bf16)s1[jg * 4 + 2], (bf16)s1[jg * 4 + 3]};
            *(bf16x4*)&Sx[ql][jg * 8 + 4 * lhi] = a;
            *(bf16x4*)&Sx[ql][32 + jg * 8 + 4 * lhi] = c;
          }
        }
      }
      BLK_BAR();                       // B1: Sx visible; all Ks reads retired
      if (s < NT) {
        if (it + 1 < t_end) {          // prefetch next K
#pragma unroll
          for (int i = 0; i < 16; ++i)
            async16(Kb + (size_t)((it + 1) * 64 + wq * 16 + i) * ND + lane * 8,
                    &Ks[wq * 16 + i][0]);
        }
        if (!skh) {                    // combine + mask + softmax + publish P,r
          float v[32];
#pragma unroll
          for (int jg = 0; jg < 4; ++jg) {
            bf16x4 a = *(const bf16x4*)&Sx[ql][jg * 8 + 4 * lhi];
            bf16x4 c = *(const bf16x4*)&Sx[ql][32 + jg * 8 + 4 * lhi];
#pragma unroll
            for (int e = 0; e < 4; ++e) {
              v[jg * 4 + e] = s0[jg * 4 + e] + (float)a[e];
              v[16 + jg * 4 + e] = s1[jg * 4 + e] + (float)c[e];
            }
          }
          if (it == qt) {
            const int k0 = it * 64;
#pragma unroll
            for (int j = 0; j < 16; ++j) {
              int kv = k0 + (j & 3) + 8 * (j >> 2) + 4 * lhi;
              if (kv > qg) v[j] = -1e30f;
              if (kv + 32 > qg) v[16 + j] = -1e30f;
            }
          }
          float mx = v[0];
#pragma unroll
          for (int j = 1; j < 32; ++j) mx = fmaxf(mx, v[j]);
          mx = fmaxf(mx, __shfl_xor(mx, 32));
          float mn = fmaxf(m_run, mx);
          float rr = exp2f(m_run - mn);
          float sum = 0.0f;
#pragma unroll
          for (int j = 0; j < 32; ++j) { v[j] = exp2f(v[j] - mn); sum += v[j]; }
          sum += __shfl_xor(sum, 32);
          m_run = mn;
          l_run = l_run * rr + sum;
          if (lhi == 0) r_lds[it & 1][ql] = rr;
#pragma unroll
          for (int jg = 0; jg < 4; ++jg) {
            bf16x4 a = {(bf16)v[jg * 4 + 0], (bf16)v[jg * 4 + 1],
                        (bf16)v[jg * 4 + 2], (bf16)v[jg * 4 + 3]};
            bf16x4 c = {(bf16)v[16 + jg * 4 + 0], (bf16)v[16 + jg * 4 + 1],
                        (bf16)v[16 + jg * 4 + 2], (bf16)v[16 + jg * 4 + 3]};
            *(bf16x4*)&Ps[it & 1][ql][jg * 8 + 4 * lhi] = a;
            *(bf16x4*)&Ps[it & 1][ql][32 + jg * 8 + 4 * lhi] = c;
          }
        }
      }
    }
    if (!skh && lhi == 0) {
      Mp[pidx * 64 + ql] = m_run;
      Lp[pidx * 64 + ql] = l_run;
      l_lds[ql] = l_run;
    }
    BLK_BAR();                         // final: l_lds visible to PV
  } else {
    // ================= consumer: PV =================
    f32x16 acc[2][4] = {};
    if (NT > 0) {
#pragma unroll
      for (int i = 0; i < 16; ++i) {   // stage V(t_begin): own 128 d-rows
        int d = dofs + i * 8 + (lane >> 3);
        async16(Vb + (size_t)d * NS + t_begin * 64 + (lane & 7) * 8,
                &Vts[dofs + i * 8][0]);
      }
    }
    for (int s = 0; s <= NT; ++s) {
      const int it = t_begin + s;
      if (s >= 1) WAVE_VM0();          // own V-DMA landed
      BLK_BAR();                       // B0
      bf16x8 paf[2][4];
      if (s >= 1) {
        const int bb = (it - 1) & 1;
#pragma unroll
        for (int qb = 0; qb < 2; ++qb)
#pragma unroll
          for (int j = 0; j < 16; ++j) {
            float rr = r_lds[bb][qb * 32 + (j & 3) + 8 * (j >> 2) + 4 * lhi];
#pragma unroll
            for (int dt = 0; dt < 4; ++dt) acc[qb][dt][j] *= rr;
          }
#pragma unroll
        for (int qb = 0; qb < 2; ++qb)
#pragma unroll
          for (int kc = 0; kc < 4; ++kc)
            paf[qb][kc] = *(const bf16x8*)&Ps[bb][qb * 32 + l31][kc * 16 + lhi * 8];
        __builtin_amdgcn_s_setprio(1);
#pragma unroll
        for (int dt = 0; dt < 2; ++dt) {
          const int d = dofs + dt * 32 + l31;
          const int swzv = (d & 7) << 3;
#pragma unroll
          for (int kc = 0; kc < 4; ++kc) {
            bf16x8 vf = *(const bf16x8*)&Vts[d][(kc * 16 + lhi * 8) ^ swzv];
            acc[0][dt] = mfma32(paf[0][kc], vf, acc[0][dt]);
            acc[1][dt] = mfma32(paf[1][kc], vf, acc[1][dt]);
          }
        }
        __builtin_amdgcn_s_setprio(0);
      }
      BLK_BAR();                       // B1
      if (s >= 1) {
        __builtin_amdgcn_s_setprio(1);
#pragma unroll
        for (int dt = 2; dt < 4; ++dt) {
          const int d = dofs + dt * 32 + l31;
          const int swzv = (d & 7) << 3;
#pragma unroll
          for (int kc = 0; kc < 4; ++kc) {
            bf16x8 vf = *(const bf16x8*)&Vts[d][(kc * 16 + lhi * 8) ^ swzv];
            acc[0][dt] = mfma32(paf[0][kc], vf, acc[0][dt]);
            acc[1][dt] = mfma32(paf[1][kc], vf, acc[1][dt]);
          }
        }
        __builtin_amdgcn_s_setprio(0);
        asm volatile("s_waitcnt lgkmcnt(0)" ::: "memory");  // Vts reads retired
        if (it < t_end) {              // stage V(it) for next step
#pragma unroll
          for (int i = 0; i < 16; ++i) {
            int d = dofs + i * 8 + (lane >> 3);
            async16(Vb + (size_t)d * NS + it * 64 + (lane & 7) * 8,
                    &Vts[dofs + i * 8][0]);
          }
        }
      }
    }
    BLK_BAR();                         // final: wait l_lds
    // epilogue: normalized bf16 partial, own 128 d, all 64 q
    bf16* Ob = Pn + (size_t)pidx * 64 * ND;
#pragma unroll
    for (int qb = 0; qb < 2; ++qb)
#pragma unroll
      for (int j = 0; j < 16; ++j) {
        const int row = qb * 32 + (j & 3) + 8 * (j >> 2) + 4 * lhi;
        float lv = l_lds[row];
        float linv = (lv > 0.0f) ? 1.0f / lv : 0.0f;
#pragma unroll
        for (int dt = 0; dt < 4; ++dt)
          Ob[(size_t)row * ND + dofs + dt * 32 + l31] = (bf16)(acc[qb][dt][j] * linv);
      }
  }
}

// ---- kernel 3: combine two KV-half partials ----
__global__ void combine_kernel(const bf16* __restrict__ Pn,
                               const float* __restrict__ Mp,
                               const float* __restrict__ Lp,
                               float* __restrict__ Out) {
  const int total = NB * NS * ND / 4;
  for (int v = blockIdx.x * 256 + threadIdx.x; v < total; v += gridDim.x * 256) {
    int e = v * 4;
    int d = e & 511;
    int s = (e >> 9) & 2047;
    int bb = e >> 20;
    int qt = s >> 6, r = s & 63;
    int p0 = (bb * 32 + qt) * 64 + r;
    int p1 = ((8 + bb) * 32 + qt) * 64 + r;
    float m0 = Mp[p0], l0 = Lp[p0], m1 = Mp[p1], l1 = Lp[p1];
    float M = fmaxf(m0, m1);
    float w0 = l0 * exp2f(m0 - M), w1 = l1 * exp2f(m1 - M);
    float inv = 1.0f / (w0 + w1);
    bf16x4 o0 = *(const bf16x4*)(Pn + (size_t)p0 * ND + d);
    bf16x4 o1 = *(const bf16x4*)(Pn + (size_t)p1 * ND + d);
    f32x4 o;
    o[0] = (w0 * (float)o0[0] + w1 * (float)o1[0]) * inv;
    o[1] = (w0 * (float)o0[1] + w1 * (float)o1[1]) * inv;
    o[2] = (w0 * (float)o0[2] + w1 * (float)o1[2]) * inv;
    o[3] = (w0 * (float)o0[3] + w1 * (float)o1[3]) * inv;
    __builtin_nontemporal_store(o, (f32x4*)(Out + e));
  }
}

extern "C" void kernel_launch(void* const* d_in, const int* in_sizes, int n_in,
                              void* d_out, int out_size, void* d_ws, size_t ws_size,
                              hipStream_t stream) {
  const float* Xk = (const float*)d_in[0];
  const float* Xv = (const float*)d_in[1];
  const float* Xq = (const float*)d_in[2];
  const float* Wq = (const float*)d_in[3];
  const float* Wk = (const float*)d_in[4];
  const float* Wv = (const float*)d_in[5];
  float* Out = (float*)d_out;

  char* ws = (char*)d_ws;
  bf16* Qb = (bf16*)(ws);                                    // 16 MB
  bf16* Kb = (bf16*)(ws + (size_t)16 * 1024 * 1024);         // 16 MB (swizzled)
  bf16* Vt = (bf16*)(ws + (size_t)32 * 1024 * 1024);         // 16 MB (transposed+swizzled)
  bf16* Wt = (bf16*)(ws + (size_t)48 * 1024 * 1024);         // 1.5 MB (pre-swizzled)
  bf16* Pn = (bf16*)(ws + (size_t)50 * 1024 * 1024);         // 32 MB partials
  float* Mp = (float*)(ws + (size_t)82 * 1024 * 1024);       // 128 KB
  float* Lp = (float*)(ws + (size_t)82 * 1024 * 1024 + 131072);

  wconv_kernel<<<dim3(8, 8, 3), 256, 0, stream>>>(Wq, Wk, Wv, Wt);
  proj_kernel<<<dim3(128, 2, 3), 512, 0, stream>>>(Xq, Xk, Xv, Wt, Qb, Kb, Vt);
  attn_kernel<<<512, 512, 0, stream>>>(Qb, Kb, Vt, Pn, Mp, Lp);
  combine_kernel<<<2048, 256, 0, stream>>>(Pn, Mp, Lp, Out);
}

// Round 17
// 145.350 us; speedup vs baseline: 1.1768x; 1.0026x over previous
//
#include <hip/hip_runtime.h>
#include <hip/hip_bf16.h>

typedef __bf16 bf16;
typedef __bf16 bf16x4 __attribute__((ext_vector_type(4)));
typedef __bf16 bf16x8 __attribute__((ext_vector_type(8)));
typedef float f32x4 __attribute__((ext_vector_type(4)));
typedef float f32x16 __attribute__((ext_vector_type(16)));

#define NB 8
#define NS 2048
#define ND 512

static __device__ __forceinline__ f32x4 mfma16(bf16x8 a, bf16x8 b, f32x4 c) {
  return __builtin_amdgcn_mfma_f32_16x16x32_bf16(a, b, c, 0, 0, 0);
}
static __device__ __forceinline__ f32x16 mfma32(bf16x8 a, bf16x8 b, f32x16 c) {
  return __builtin_amdgcn_mfma_f32_32x32x16_bf16(a, b, c, 0, 0, 0);
}
static __device__ __forceinline__ void async16(const bf16* g, bf16* l) {
  __builtin_amdgcn_global_load_lds((const __attribute__((address_space(1))) void*)g,
                                   (__attribute__((address_space(3))) void*)l, 16, 0, 0);
}

#define WAVE_VM0() asm volatile("s_waitcnt vmcnt(0)" ::: "memory")
#define BLK_BAR() do { asm volatile("s_waitcnt lgkmcnt(0)" ::: "memory"); \
  __builtin_amdgcn_s_barrier(); __builtin_amdgcn_sched_barrier(0); } while (0)

// ---- kernel 0: W[k][n] (f32) -> Wt[z][n][k^((n&7)<<3)] (bf16, pre-swizzled).
// Wq additionally scaled by rsqrt(512)*log2e (folds softmax scale into Q).
__global__ void wconv_kernel(const float* __restrict__ Wq,
                             const float* __restrict__ Wk,
                             const float* __restrict__ Wv,
                             bf16* __restrict__ Wt) {
  __shared__ float buf[64][65];
  const int z = blockIdx.z;
  const float* W = (z == 0) ? Wq : (z == 1) ? Wk : Wv;
  const float scale = (z == 0) ? 0.063763537f : 1.0f;
  const int k0 = blockIdx.x * 64, n0 = blockIdx.y * 64;
  const int t = threadIdx.x;
#pragma unroll
  for (int i = 0; i < 16; ++i) {
    int idx = i * 256 + t;
    int kk = idx >> 6, nn = idx & 63;
    buf[kk][nn] = W[(size_t)(k0 + kk) * 512 + n0 + nn];
  }
  __syncthreads();
#pragma unroll
  for (int i = 0; i < 16; ++i) {
    int idx = i * 256 + t;
    int nn = idx >> 6, kk = idx & 63;
    Wt[(size_t)z * 262144 + (size_t)(n0 + nn) * 512 + k0 + (kk ^ ((nn & 7) << 3))] =
        (bf16)(buf[kk][nn] * scale);
  }
}

// ---- kernel 1: fused 3x projection, 128x256 tiles ----
// Reg-staged A pipeline + W global_load_lds with counted vmcnt. 8 waves (2Mx4N).
// z=0: Q plain; z=1: K col-swizzled; z=2: V^T [B][512][2048] s-swizzled.
__launch_bounds__(512)
__global__ void proj_kernel(const float* __restrict__ Xq,
                            const float* __restrict__ Xk,
                            const float* __restrict__ Xv,
                            const bf16* __restrict__ Wt,
                            bf16* __restrict__ Cq,
                            bf16* __restrict__ Ck,
                            bf16* __restrict__ Cv) {
  __shared__ bf16 As[2][128][72];     // 36 KB
  __shared__ bf16 WsL[2][16384];      // 64 KB: [256 n][64 k] linear (DMA dest)
  const int z = blockIdx.z;
  const float* A = (z == 0) ? Xq : (z == 1) ? Xk : Xv;
  const bf16* Wz = Wt + (size_t)z * 262144;
  bf16* C = (z == 0) ? Cq : (z == 1) ? Ck : Cv;

  const int t = threadIdx.x;
  const int lane = t & 63;
  const int w = t >> 6;
  const int wr = w >> 2, wc = w & 3;            // 2 x 4 waves, 64x64 each
  const int bxr = blockIdx.x;
  const int mt = (bxr & 7) * 16 + (bxr >> 3);   // batch-pinned M-tile
  const int bm = mt * 128;
  const int bn = blockIdx.y * 256;
  const int r0 = t >> 4, seg = t & 15;          // r0 in [0,32)

  f32x4 acc[4][4] = {};
  float4 ar[4];                                 // A prefetch regs (static idx)

  auto loadA = [&](int kc) {
#pragma unroll
    for (int p = 0; p < 4; ++p)
      ar[p] = *(const float4*)(A + (size_t)(bm + p * 32 + r0) * 512 + kc * 64 + seg * 4);
  };
  auto writeA = [&](int bufi) {
#pragma unroll
    for (int p = 0; p < 4; ++p) {
      bf16x4 o = {(bf16)ar[p].x, (bf16)ar[p].y, (bf16)ar[p].z, (bf16)ar[p].w};
      *(bf16x4*)&As[bufi][p * 32 + r0][seg * 4] = o;
    }
  };
  // W DMA: stripe i covers rows i*64 + (t>>3), chunk (t&7)*8 -> LDS offset
  // i*4096 + t*8 bf16 (linear in t x 16B: rule-21 compliant).
  auto issueW = [&](int kc, int bufi) {
    const int n8 = t >> 3, sg8 = t & 7;
#pragma unroll
    for (int i = 0; i < 4; ++i)
      async16(Wz + (size_t)(bn + i * 64 + n8) * 512 + kc * 64 + sg8 * 8,
              &WsL[bufi][i * 4096 + t * 8]);
  };

  // prologue: A0 -> regs -> LDS; W0 DMA; A1 in flight across the barrier
  loadA(0);
  WAVE_VM0();
  writeA(0);
  issueW(0, 0);                     // queue: W0(4)
  loadA(1);                         // queue: W0(4), A1(4)
  asm volatile("s_waitcnt vmcnt(4) lgkmcnt(0)" ::: "memory");   // W0 landed
  __builtin_amdgcn_s_barrier();
  __builtin_amdgcn_sched_barrier(0);

#pragma unroll
  for (int kc = 0; kc < 8; ++kc) {
    const int c = kc & 1;
    if (kc < 7) issueW(kc + 1, c ^ 1);   // queue: A(kc+1)(4) + W(kc+1)(4)
    const int arow = lane & 15, kq = (lane >> 4) * 8;
#pragma unroll
    for (int kk = 0; kk < 2; ++kk) {
      bf16x8 af[4], bfr[4];
#pragma unroll
      for (int mi = 0; mi < 4; ++mi)
        af[mi] = *(const bf16x8*)&As[c][wr * 64 + mi * 16 + arow][kk * 32 + kq];
#pragma unroll
      for (int ni = 0; ni < 4; ++ni) {
        int n = wc * 64 + ni * 16 + arow;
        bfr[ni] = *(const bf16x8*)&WsL[c][n * 64 + ((kk * 32 + kq) ^ ((n & 7) << 3))];
      }
#pragma unroll
      for (int mi = 0; mi < 4; ++mi)
#pragma unroll
        for (int ni = 0; ni < 4; ++ni)
          acc[mi][ni] = mfma16(af[mi], bfr[ni], acc[mi][ni]);
    }
    if (kc < 7) {
      asm volatile("s_waitcnt vmcnt(4)" ::: "memory");   // A(kc+1) landed
      writeA(c ^ 1);
      if (kc < 6) {
        loadA(kc + 2);               // queue: W(kc+1)(4) + A(kc+2)(4)
        asm volatile("s_waitcnt vmcnt(4) lgkmcnt(0)" ::: "memory");  // W landed
      } else {
        asm volatile("s_waitcnt vmcnt(0) lgkmcnt(0)" ::: "memory");
      }
      __builtin_amdgcn_s_barrier();
      __builtin_amdgcn_sched_barrier(0);
    }
  }

  const int row0 = (lane >> 4) * 4, col = lane & 15;
#pragma unroll
  for (int mi = 0; mi < 4; ++mi)
#pragma unroll
    for (int ni = 0; ni < 4; ++ni) {
      int cg = bn + wc * 64 + ni * 16 + col;
#pragma unroll
      for (int j = 0; j < 4; ++j) {
        int rg = bm + wr * 64 + mi * 16 + row0 + j;
        bf16 o = (bf16)acc[mi][ni][j];
        if (z == 0) {
          C[(size_t)rg * ND + cg] = o;
        } else if (z == 1) {
          C[(size_t)rg * ND + (cg ^ ((rg & 7) << 3))] = o;
        } else {
          int bb = rg >> 11, s = rg & 2047;
          int ss = (s & ~63) | ((s & 63) ^ ((cg & 7) << 3));
          C[(size_t)bb * (ND * NS) + (size_t)cg * NS + ss] = o;
        }
      }
    }
}

// ---- kernel 2: wave-specialized pipelined causal flash attention ----
// Round-11 proven configuration (attn ~78us) — byte-identical.
__launch_bounds__(512, 2)
__global__ void attn_kernel(const bf16* __restrict__ Qg,
                            const bf16* __restrict__ Kg,    // col-swizzled
                            const bf16* __restrict__ Vtg,   // V^T, s-swizzled
                            bf16* __restrict__ Pn,
                            float* __restrict__ Mp,
                            float* __restrict__ Lp) {
  __shared__ bf16 Ks[64][512];      // 64 KB
  __shared__ bf16 Vts[512][64];     // 64 KB
  __shared__ bf16 Sx[64][68];       // 8.5 KB  (k-half partial exchange)
  __shared__ bf16 Ps[2][64][76];    // 19 KB   (P dbuf)
  __shared__ float r_lds[2][64];
  __shared__ float l_lds[64];

  const int t = threadIdx.x;
  const int lane = t & 63;
  const int w = t >> 6;
  const int l31 = lane & 31, lhi = lane >> 5;
  const int wq = w & 3;
  const bool isQK = w < 4;
  const int qh = wq & 1, skh = wq >> 1;
  const int dofs = wq * 128;

  const int id = blockIdx.x;
  const int b = id & 7;
  const int qt = 31 - ((id >> 3) & 31);
  const int h = id >> 8;
  const int q0 = qt * 64;
  const int nt = qt + 1, mid = (nt + 1) >> 1;
  const int t_begin = h ? mid : 0;
  const int t_end = h ? nt : mid;
  const int NT = t_end - t_begin;
  const int pidx = (h * 8 + b) * 32 + qt;

  const bf16* Qb = Qg + (size_t)b * NS * ND;
  const bf16* Kb = Kg + (size_t)b * NS * ND;
  const bf16* Vb = Vtg + (size_t)b * ND * NS;

  if (isQK) {
    // ================= producer: QK^T + online softmax =================
    const int ql = qh * 32 + l31;
    const int qg = q0 + ql;
    bf16x8 qf[16];
    float m_run = -1e30f, l_run = 0.0f;
    if (NT > 0) {
      const bf16* qrow = Qb + (size_t)qg * ND + skh * 256 + lhi * 8;
#pragma unroll
      for (int kc = 0; kc < 16; ++kc) qf[kc] = *(const bf16x8*)(qrow + kc * 16);
#pragma unroll
      for (int i = 0; i < 16; ++i)   // stage K(t_begin): own 16 rows
        async16(Kb + (size_t)(t_begin * 64 + wq * 16 + i) * ND + lane * 8,
                &Ks[wq * 16 + i][0]);
    }
    for (int s = 0; s <= NT; ++s) {
      const int it = t_begin + s;
      f32x16 s0 = {}, s1 = {};
      if (s < NT) WAVE_VM0();          // own K-DMA (and Q frags at s=0) landed
      BLK_BAR();                       // B0: all K rows visible; Ps/r published
      if (s < NT) {
        __builtin_amdgcn_s_setprio(1);
#pragma unroll
        for (int kc = 0; kc < 16; ++kc) {
          const int colk = (skh * 256 + kc * 16 + lhi * 8) ^ ((l31 & 7) << 3);
          bf16x8 kf0 = *(const bf16x8*)&Ks[l31][colk];
          bf16x8 kf1 = *(const bf16x8*)&Ks[32 + l31][colk];
          s0 = mfma32(kf0, qf[kc], s0);   // D[kv][q], col=lane=q
          s1 = mfma32(kf1, qf[kc], s1);
        }
        __builtin_amdgcn_s_setprio(0);
        if (skh) {                     // publish K-half partial (bf16)
#pragma unroll
          for (int jg = 0; jg < 4; ++jg) {
            bf16x4 a = {(bf16)s0[jg * 4 + 0], (bf16)s0[jg * 4 + 1],
                        (bf16)s0[jg * 4 + 2], (bf16)s0[jg * 4 + 3]};
            bf16x4 c = {(bf16)s1[jg * 4 + 0], (bf16)s1[jg * 4 + 1],
                        (bf16)s1[jg * 4 + 2], (bf16)s1[jg * 4 + 3]};
            *(bf16x4*)&Sx[ql][jg * 8 + 4 * lhi] = a;
            *(bf16x4*)&Sx[ql][32 + jg * 8 + 4 * lhi] = c;
          }
        }
      }
      BLK_BAR();                       // B1: Sx visible; all Ks reads retired
      if (s < NT) {
        if (it + 1 < t_end) {          // prefetch next K
#pragma unroll
          for (int i = 0; i < 16; ++i)
            async16(Kb + (size_t)((it + 1) * 64 + wq * 16 + i) * ND + lane * 8,
                    &Ks[wq * 16 + i][0]);
        }
        if (!skh) {                    // combine + mask + softmax + publish P,r
          float v[32];
#pragma unroll
          for (int jg = 0; jg < 4; ++jg) {
            bf16x4 a = *(const bf16x4*)&Sx[ql][jg * 8 + 4 * lhi];
            bf16x4 c = *(const bf16x4*)&Sx[ql][32 + jg * 8 + 4 * lhi];
#pragma unroll
            for (int e = 0; e < 4; ++e) {
              v[jg * 4 + e] = s0[jg * 4 + e] + (float)a[e];
              v[16 + jg * 4 + e] = s1[jg * 4 + e] + (float)c[e];
            }
          }
          if (it == qt) {
            const int k0 = it * 64;
#pragma unroll
            for (int j = 0; j < 16; ++j) {
              int kv = k0 + (j & 3) + 8 * (j >> 2) + 4 * lhi;
              if (kv > qg) v[j] = -1e30f;
              if (kv + 32 > qg) v[16 + j] = -1e30f;
            }
          }
          float mx = v[0];
#pragma unroll
          for (int j = 1; j < 32; ++j) mx = fmaxf(mx, v[j]);
          mx = fmaxf(mx, __shfl_xor(mx, 32));
          float mn = fmaxf(m_run, mx);
          float rr = exp2f(m_run - mn);
          float sum = 0.0f;
#pragma unroll
          for (int j = 0; j < 32; ++j) { v[j] = exp2f(v[j] - mn); sum += v[j]; }
          sum += __shfl_xor(sum, 32);
          m_run = mn;
          l_run = l_run * rr + sum;
          if (lhi == 0) r_lds[it & 1][ql] = rr;
#pragma unroll
          for (int jg = 0; jg < 4; ++jg) {
            bf16x4 a = {(bf16)v[jg * 4 + 0], (bf16)v[jg * 4 + 1],
                        (bf16)v[jg * 4 + 2], (bf16)v[jg * 4 + 3]};
            bf16x4 c = {(bf16)v[16 + jg * 4 + 0], (bf16)v[16 + jg * 4 + 1],
                        (bf16)v[16 + jg * 4 + 2], (bf16)v[16 + jg * 4 + 3]};
            *(bf16x4*)&Ps[it & 1][ql][jg * 8 + 4 * lhi] = a;
            *(bf16x4*)&Ps[it & 1][ql][32 + jg * 8 + 4 * lhi] = c;
          }
        }
      }
    }
    if (!skh && lhi == 0) {
      Mp[pidx * 64 + ql] = m_run;
      Lp[pidx * 64 + ql] = l_run;
      l_lds[ql] = l_run;
    }
    BLK_BAR();                         // final: l_lds visible to PV
  } else {
    // ================= consumer: PV =================
    f32x16 acc[2][4] = {};
    if (NT > 0) {
#pragma unroll
      for (int i = 0; i < 16; ++i) {   // stage V(t_begin): own 128 d-rows
        int d = dofs + i * 8 + (lane >> 3);
        async16(Vb + (size_t)d * NS + t_begin * 64 + (lane & 7) * 8,
                &Vts[dofs + i * 8][0]);
      }
    }
    for (int s = 0; s <= NT; ++s) {
      const int it = t_begin + s;
      if (s >= 1) WAVE_VM0();          // own V-DMA landed
      BLK_BAR();                       // B0
      bf16x8 paf[2][4];
      if (s >= 1) {
        const int bb = (it - 1) & 1;
#pragma unroll
        for (int qb = 0; qb < 2; ++qb)
#pragma unroll
          for (int j = 0; j < 16; ++j) {
            float rr = r_lds[bb][qb * 32 + (j & 3) + 8 * (j >> 2) + 4 * lhi];
#pragma unroll
            for (int dt = 0; dt < 4; ++dt) acc[qb][dt][j] *= rr;
          }
#pragma unroll
        for (int qb = 0; qb < 2; ++qb)
#pragma unroll
          for (int kc = 0; kc < 4; ++kc)
            paf[qb][kc] = *(const bf16x8*)&Ps[bb][qb * 32 + l31][kc * 16 + lhi * 8];
        __builtin_amdgcn_s_setprio(1);
#pragma unroll
        for (int dt = 0; dt < 2; ++dt) {
          const int d = dofs + dt * 32 + l31;
          const int swzv = (d & 7) << 3;
#pragma unroll
          for (int kc = 0; kc < 4; ++kc) {
            bf16x8 vf = *(const bf16x8*)&Vts[d][(kc * 16 + lhi * 8) ^ swzv];
            acc[0][dt] = mfma32(paf[0][kc], vf, acc[0][dt]);
            acc[1][dt] = mfma32(paf[1][kc], vf, acc[1][dt]);
          }
        }
        __builtin_amdgcn_s_setprio(0);
      }
      BLK_BAR();                       // B1
      if (s >= 1) {
        __builtin_amdgcn_s_setprio(1);
#pragma unroll
        for (int dt = 2; dt < 4; ++dt) {
          const int d = dofs + dt * 32 + l31;
          const int swzv = (d & 7) << 3;
#pragma unroll
          for (int kc = 0; kc < 4; ++kc) {
            bf16x8 vf = *(const bf16x8*)&Vts[d][(kc * 16 + lhi * 8) ^ swzv];
            acc[0][dt] = mfma32(paf[0][kc], vf, acc[0][dt]);
            acc[1][dt] = mfma32(paf[1][kc], vf, acc[1][dt]);
          }
        }
        __builtin_amdgcn_s_setprio(0);
        asm volatile("s_waitcnt lgkmcnt(0)" ::: "memory");  // Vts reads retired
        if (it < t_end) {              // stage V(it) for next step
#pragma unroll
          for (int i = 0; i < 16; ++i) {
            int d = dofs + i * 8 + (lane >> 3);
            async16(Vb + (size_t)d * NS + it * 64 + (lane & 7) * 8,
                    &Vts[dofs + i * 8][0]);
          }
        }
      }
    }
    BLK_BAR();                         // final: wait l_lds
    // epilogue: normalized bf16 partial, own 128 d, all 64 q
    bf16* Ob = Pn + (size_t)pidx * 64 * ND;
#pragma unroll
    for (int qb = 0; qb < 2; ++qb)
#pragma unroll
      for (int j = 0; j < 16; ++j) {
        const int row = qb * 32 + (j & 3) + 8 * (j >> 2) + 4 * lhi;
        float lv = l_lds[row];
        float linv = (lv > 0.0f) ? 1.0f / lv : 0.0f;
#pragma unroll
        for (int dt = 0; dt < 4; ++dt)
          Ob[(size_t)row * ND + dofs + dt * 32 + l31] = (bf16)(acc[qb][dt][j] * linv);
      }
  }
}

// ---- kernel 3: combine two KV-half partials ----
__global__ void combine_kernel(const bf16* __restrict__ Pn,
                               const float* __restrict__ Mp,
                               const float* __restrict__ Lp,
                               float* __restrict__ Out) {
  const int total = NB * NS * ND / 4;
  for (int v = blockIdx.x * 256 + threadIdx.x; v < total; v += gridDim.x * 256) {
    int e = v * 4;
    int d = e & 511;
    int s = (e >> 9) & 2047;
    int bb = e >> 20;
    int qt = s >> 6, r = s & 63;
    int p0 = (bb * 32 + qt) * 64 + r;
    int p1 = ((8 + bb) * 32 + qt) * 64 + r;
    float m0 = Mp[p0], l0 = Lp[p0], m1 = Mp[p1], l1 = Lp[p1];
    float M = fmaxf(m0, m1);
    float w0 = l0 * exp2f(m0 - M), w1 = l1 * exp2f(m1 - M);
    float inv = 1.0f / (w0 + w1);
    bf16x4 o0 = *(const bf16x4*)(Pn + (size_t)p0 * ND + d);
    bf16x4 o1 = *(const bf16x4*)(Pn + (size_t)p1 * ND + d);
    f32x4 o;
    o[0] = (w0 * (float)o0[0] + w1 * (float)o1[0]) * inv;
    o[1] = (w0 * (float)o0[1] + w1 * (float)o1[1]) * inv;
    o[2] = (w0 * (float)o0[2] + w1 * (float)o1[2]) * inv;
    o[3] = (w0 * (float)o0[3] + w1 * (float)o1[3]) * inv;
    __builtin_nontemporal_store(o, (f32x4*)(Out + e));
  }
}

extern "C" void kernel_launch(void* const* d_in, const int* in_sizes, int n_in,
                              void* d_out, int out_size, void* d_ws, size_t ws_size,
                              hipStream_t stream) {
  const float* Xk = (const float*)d_in[0];
  const float* Xv = (const float*)d_in[1];
  const float* Xq = (const float*)d_in[2];
  const float* Wq = (const float*)d_in[3];
  const float* Wk = (const float*)d_in[4];
  const float* Wv = (const float*)d_in[5];
  float* Out = (float*)d_out;

  char* ws = (char*)d_ws;
  bf16* Qb = (bf16*)(ws);                                    // 16 MB
  bf16* Kb = (bf16*)(ws + (size_t)16 * 1024 * 1024);         // 16 MB (swizzled)
  bf16* Vt = (bf16*)(ws + (size_t)32 * 1024 * 1024);         // 16 MB (transposed+swizzled)
  bf16* Wt = (bf16*)(ws + (size_t)48 * 1024 * 1024);         // 1.5 MB (pre-swizzled)
  bf16* Pn = (bf16*)(ws + (size_t)50 * 1024 * 1024);         // 32 MB partials
  float* Mp = (float*)(ws + (size_t)82 * 1024 * 1024);       // 128 KB
  float* Lp = (float*)(ws + (size_t)82 * 1024 * 1024 + 131072);

  wconv_kernel<<<dim3(8, 8, 3), 256, 0, stream>>>(Wq, Wk, Wv, Wt);
  proj_kernel<<<dim3(128, 2, 3), 512, 0, stream>>>(Xq, Xk, Xv, Wt, Qb, Kb, Vt);
  attn_kernel<<<512, 512, 0, stream>>>(Qb, Kb, Vt, Pn, Mp, Lp);
  combine_kernel<<<2048, 256, 0, stream>>>(Pn, Mp, Lp, Out);
}